// Round 7
// baseline (44.914 us; speedup 1.0000x reference)
//
#include <hip/hip_runtime.h>
#include <hip/hip_bf16.h>

// ---------------------------------------------------------------------------
// VQC_Net: probs[b, c] = ( sum_j U[c][j] * amp[b][j] )^2,  c = 0..9
// Structure: T = U rows 0..9 precomputed to d_ws by build_T; main kernel
// reads T with wave-uniform indices (s_load, K$-hot), c-outer matvec.
// R7 delta: NO LDS, NO barriers — each thread stores its 10 outputs
// directly (stride-40B dwords). CDNA L2 is write-back with byte-enable
// dirty masks (no RFO): a wave's 10 back-to-back stores fully cover a
// contiguous 2560B span, so HBM still sees full-line writes. Removes the
// per-tile rendezvous convoy and the LDS round-trip entirely; read and
// write streams flow continuously. Persistent 4-tile blocks + x prefetch.
// amp build:
//   amp[0][k]  = prod_j ( (k>>j)&1 ? x0j : 1-x0j )                 (no sqrt)
//   amp[b][k]  = sqrt(hi)*sqrt(lo) factored, big-endian bits       (b >= 1)
// ---------------------------------------------------------------------------

#if defined(__has_builtin)
#if __has_builtin(__builtin_amdgcn_sqrtf)
#define FSQRT(x) __builtin_amdgcn_sqrtf(x)
#endif
#endif
#ifndef FSQRT
#define FSQRT(x) sqrtf(x)
#endif

__device__ __forceinline__ float ry_el(float c, float s, int i, int j) {
    return (i == j) ? c : (i ? s : -s);  // ry = [[c,-s],[s,c]]
}

__global__ void build_T(const float* __restrict__ theta, float* __restrict__ T) {
    int t = threadIdx.x;
    if (t >= 160) return;
    int c = t >> 4;   // row of U (class)
    int j = t & 15;   // col of U (amp index)

    float co1[4], si1[4], co2[4], si2[4];
#pragma unroll
    for (int q = 0; q < 4; ++q) {
        float h1 = 0.5f * theta[q];
        float h2 = 0.5f * theta[4 + q];
        co1[q] = cosf(h1); si1[q] = sinf(h1);
        co2[q] = cosf(h2); si2[q] = sinf(h2);
    }
    float acc = 0.0f;
#pragma unroll
    for (int k = 0; k < 16; ++k) {
        int k0 = k & 1, k1 = (k >> 1) & 1, k2 = (k >> 2) & 1, k3 = (k >> 3) & 1;
        float r2 = ry_el(co2[0], si2[0], c & 1, k0)
                 * ry_el(co2[1], si2[1], (c >> 1) & 1, k1)
                 * ry_el(co2[2], si2[2], (c >> 2) & 1, k2)
                 * ry_el(co2[3], si2[3], (c >> 3) & 1, k3);
        float r1 = ry_el(co1[0], si1[0], k0, j & 1)
                 * ry_el(co1[1], si1[1], k1, (j >> 1) & 1)
                 * ry_el(co1[2], si1[2], k2, (j >> 2) & 1)
                 * ry_el(co1[3], si1[3], k3, (j >> 3) & 1);
        int sgn = (k0 & k1) ^ (k1 & k2) ^ (k2 & k3) ^ (k0 & k3);
        acc = fmaf(sgn ? -r2 : r2, r1, acc);
    }
    T[c * 16 + j] = acc;   // row-major, matches matvec read order
}

// amp for the generic (b>=1) path: big-endian bits, squared probs, sqrt
__device__ __forceinline__ void amp_resolve(float4 xv, float amp[16]) {
    float p0 = xv.x * xv.x, p1 = xv.y * xv.y;
    float p2 = xv.z * xv.z, p3 = xv.w * xv.w;
    float hi[4] = { (1.0f - p0) * (1.0f - p1), (1.0f - p0) * p1,
                    p0 * (1.0f - p1),          p0 * p1 };
    float lo[4] = { (1.0f - p2) * (1.0f - p3), (1.0f - p2) * p3,
                    p2 * (1.0f - p3),          p2 * p3 };
    float sh[4], sl[4];
#pragma unroll
    for (int i = 0; i < 4; ++i) { sh[i] = FSQRT(hi[i]); sl[i] = FSQRT(lo[i]); }
#pragma unroll
    for (int k = 0; k < 16; ++k)
        amp[k] = sh[k >> 2] * sl[k & 3];
}

// amp for sample 0: little-endian bits, raw products, no sqrt
__device__ __forceinline__ void amp_prob2amp(float4 xv, float amp[16]) {
    float lo[4] = { (1.0f - xv.x) * (1.0f - xv.y), xv.x * (1.0f - xv.y),
                    (1.0f - xv.x) * xv.y,          xv.x * xv.y };
    float hi[4] = { (1.0f - xv.z) * (1.0f - xv.w), xv.z * (1.0f - xv.w),
                    (1.0f - xv.z) * xv.w,          xv.z * xv.w };
#pragma unroll
    for (int k = 0; k < 16; ++k)
        amp[k] = lo[k & 3] * hi[k >> 2];
}

#define TILES 4   // 4 x 256 samples per block; 2M / 1024 = 2048 blocks exact

__global__ __launch_bounds__(256, 8) void vqc_main(const float4* __restrict__ x,
                                                   const float* __restrict__ T,
                                                   float* __restrict__ out,
                                                   int nsamp) {
    int tid = threadIdx.x;
    long long base = (long long)blockIdx.x * (TILES * 256);

    // prefetch tile 0
    float4 xv;
    {
        long long b0 = base + tid;
        if (b0 < nsamp) xv = x[b0];
    }

#pragma unroll
    for (int t = 0; t < TILES; ++t) {
        long long b = base + (long long)t * 256 + tid;
        bool valid = b < nsamp;
        float4 cur = xv;

        // issue next tile's load before this tile's compute (latency overlap)
        if (t + 1 < TILES) {
            long long bn = b + 256;
            if (bn < nsamp) xv = x[bn];
        }

        if (valid) {
            float amp[16];
            if (b == 0) amp_prob2amp(cur, amp);
            else        amp_resolve(cur, amp);

            // 10x16 matvec; T[] indices wave-uniform -> scalar loads feed
            // v_fmac as the single SGPR operand. unroll 2: ~32 live T-SGPRs.
            float* ob = out + b * 10;
#pragma unroll 2
            for (int c = 0; c < 10; ++c) {
                float s = 0.0f;
#pragma unroll
                for (int jj = 0; jj < 16; ++jj)
                    s = fmaf(T[c * 16 + jj], amp[jj], s);
                // direct store: wave's 10 stores cover a contiguous 2560B
                // span; L2 byte-enable merging -> full-line HBM writes.
                ob[c] = s * s;
            }
        }
    }
}

extern "C" void kernel_launch(void* const* d_in, const int* in_sizes, int n_in,
                              void* d_out, int out_size, void* d_ws, size_t ws_size,
                              hipStream_t stream) {
    const float* x = (const float*)d_in[0];      // [B,4] f32
    const float* theta = (const float*)d_in[1];  // [8]   f32
    float* out = (float*)d_out;                  // [B,10] f32
    float* T = (float*)d_ws;                     // 160 floats scratch

    int nsamp = in_sizes[0] / 4;

    build_T<<<1, 192, 0, stream>>>(theta, T);

    int spb = TILES * 256;
    int blocks = (nsamp + spb - 1) / spb;
    vqc_main<<<blocks, 256, 0, stream>>>((const float4*)x, T, out, nsamp);
}

// Round 8
// 30.543 us; speedup vs baseline: 1.4705x; 1.4705x over previous
//
#include <hip/hip_runtime.h>
#include <hip/hip_bf16.h>

// ---------------------------------------------------------------------------
// VQC_Net: probs[b, c] = ( sum_j U[c][j] * amp[b][j] )^2,  c = 0..9
// Structure: T = U rows 0..9 precomputed to d_ws by build_T; main kernel
// reads T with wave-uniform indices (s_load, K$-hot), c-outer matvec,
// LDS-staged coalesced output flush; persistent 4-tile blocks + x prefetch.
// R8 delta: WAVE-PRIVATE LDS staging -> ZERO barriers. Each wave stages its
// own 64 samples (2560B slice); flush reads only own-wave writes, so
// s_waitcnt lgkmcnt(0) alone orders write->read. Waves are fully independent
// streaming pipelines; no rendezvous, no convoy on the slowest wave.
// (R7 lesson: direct stride-40B stores = 10x line-request amplification ->
//  2.2 TB/s. LDS transpose is essential. R6 lesson: barriers that drain
//  vmcnt convoy the store stream; here there are no barriers at all.)
// amp build:
//   amp[0][k]  = prod_j ( (k>>j)&1 ? x0j : 1-x0j )                 (no sqrt)
//   amp[b][k]  = sqrt(hi)*sqrt(lo) factored, big-endian bits       (b >= 1)
// ---------------------------------------------------------------------------

#if defined(__has_builtin)
#if __has_builtin(__builtin_amdgcn_sqrtf)
#define FSQRT(x) __builtin_amdgcn_sqrtf(x)
#endif
#endif
#ifndef FSQRT
#define FSQRT(x) sqrtf(x)
#endif

__device__ __forceinline__ float ry_el(float c, float s, int i, int j) {
    return (i == j) ? c : (i ? s : -s);  // ry = [[c,-s],[s,c]]
}

__global__ void build_T(const float* __restrict__ theta, float* __restrict__ T) {
    int t = threadIdx.x;
    if (t >= 160) return;
    int c = t >> 4;   // row of U (class)
    int j = t & 15;   // col of U (amp index)

    float co1[4], si1[4], co2[4], si2[4];
#pragma unroll
    for (int q = 0; q < 4; ++q) {
        float h1 = 0.5f * theta[q];
        float h2 = 0.5f * theta[4 + q];
        co1[q] = cosf(h1); si1[q] = sinf(h1);
        co2[q] = cosf(h2); si2[q] = sinf(h2);
    }
    float acc = 0.0f;
#pragma unroll
    for (int k = 0; k < 16; ++k) {
        int k0 = k & 1, k1 = (k >> 1) & 1, k2 = (k >> 2) & 1, k3 = (k >> 3) & 1;
        float r2 = ry_el(co2[0], si2[0], c & 1, k0)
                 * ry_el(co2[1], si2[1], (c >> 1) & 1, k1)
                 * ry_el(co2[2], si2[2], (c >> 2) & 1, k2)
                 * ry_el(co2[3], si2[3], (c >> 3) & 1, k3);
        float r1 = ry_el(co1[0], si1[0], k0, j & 1)
                 * ry_el(co1[1], si1[1], k1, (j >> 1) & 1)
                 * ry_el(co1[2], si1[2], k2, (j >> 2) & 1)
                 * ry_el(co1[3], si1[3], k3, (j >> 3) & 1);
        int sgn = (k0 & k1) ^ (k1 & k2) ^ (k2 & k3) ^ (k0 & k3);
        acc = fmaf(sgn ? -r2 : r2, r1, acc);
    }
    T[c * 16 + j] = acc;   // row-major, matches matvec read order
}

// amp for the generic (b>=1) path: big-endian bits, squared probs, sqrt
__device__ __forceinline__ void amp_resolve(float4 xv, float amp[16]) {
    float p0 = xv.x * xv.x, p1 = xv.y * xv.y;
    float p2 = xv.z * xv.z, p3 = xv.w * xv.w;
    float hi[4] = { (1.0f - p0) * (1.0f - p1), (1.0f - p0) * p1,
                    p0 * (1.0f - p1),          p0 * p1 };
    float lo[4] = { (1.0f - p2) * (1.0f - p3), (1.0f - p2) * p3,
                    p2 * (1.0f - p3),          p2 * p3 };
    float sh[4], sl[4];
#pragma unroll
    for (int i = 0; i < 4; ++i) { sh[i] = FSQRT(hi[i]); sl[i] = FSQRT(lo[i]); }
#pragma unroll
    for (int k = 0; k < 16; ++k)
        amp[k] = sh[k >> 2] * sl[k & 3];
}

// amp for sample 0: little-endian bits, raw products, no sqrt
__device__ __forceinline__ void amp_prob2amp(float4 xv, float amp[16]) {
    float lo[4] = { (1.0f - xv.x) * (1.0f - xv.y), xv.x * (1.0f - xv.y),
                    (1.0f - xv.x) * xv.y,          xv.x * xv.y };
    float hi[4] = { (1.0f - xv.z) * (1.0f - xv.w), xv.z * (1.0f - xv.w),
                    (1.0f - xv.z) * xv.w,          xv.z * xv.w };
#pragma unroll
    for (int k = 0; k < 16; ++k)
        amp[k] = lo[k & 3] * hi[k >> 2];
}

#define TILES 4   // 4 x 256 samples per block; 2M / 1024 = 2048 blocks exact

__global__ __launch_bounds__(256, 8) void vqc_main(const float4* __restrict__ x,
                                                   const float* __restrict__ T,
                                                   float* __restrict__ out,
                                                   int nsamp) {
    // wave-private double-buffered staging: [wave][buf][640 floats]
    __shared__ float sBuf[4][2][640];   // 20 KB

    int tid = threadIdx.x;
    int wid = tid >> 6;
    int lane = tid & 63;

    long long base = (long long)blockIdx.x * (TILES * 256);

    // prefetch tile 0
    float4 xv;
    {
        long long b0 = base + tid;
        if (b0 < nsamp) xv = x[b0];
    }

#pragma unroll
    for (int t = 0; t < TILES; ++t) {
        long long tileStart = base + (long long)t * 256;
        long long b = tileStart + tid;
        float4 cur = xv;

        // issue next tile's load before this tile's compute (latency overlap)
        if (t + 1 < TILES) {
            long long bn = b + 256;
            if (bn < nsamp) xv = x[bn];
        }

        int p = t & 1;
        float* myBuf = sBuf[wid][p];

        if (b < nsamp) {
            float amp[16];
            if (b == 0) amp_prob2amp(cur, amp);
            else        amp_resolve(cur, amp);

            // 10x16 matvec; T[] indices wave-uniform -> scalar loads feed
            // v_fmac as the single SGPR operand. unroll 2: ~32 live T-SGPRs.
#pragma unroll 2
            for (int c = 0; c < 10; ++c) {
                float s = 0.0f;
#pragma unroll
                for (int jj = 0; jj < 16; ++jj)
                    s = fmaf(T[c * 16 + jj], amp[jj], s);
                myBuf[lane * 10 + c] = s * s;   // 4-way bank alias: ~free
            }
        }

        // drain OWN ds_writes (and last tile's flush reads) - intra-wave only,
        // no barrier: flush below reads only this wave's slice.
        asm volatile("s_waitcnt lgkmcnt(0)" ::: "memory");

        long long waveBase = tileStart + (long long)(wid << 6);
        long long wrem = (long long)nsamp - waveBase;
        if (wrem >= 64) {
            // wave's 64 samples = 2560B contiguous in out, 16B-aligned
            float4* ov = (float4*)(out + waveBase * 10);
            const float4* sv = (const float4*)myBuf;
#pragma unroll
            for (int i = lane; i < 160; i += 64)
                ov[i] = sv[i];
        } else if (wrem > 0) {
            int n = (int)wrem * 10;
            for (int i = lane; i < n; i += 64)
                out[waveBase * 10 + i] = myBuf[i];
        }
        // WAR on buffer p (reused at t+2): protected by the lgkmcnt(0) at
        // t+1, which drains this tile's flush ds_reads before t+2's writes.
    }
}

extern "C" void kernel_launch(void* const* d_in, const int* in_sizes, int n_in,
                              void* d_out, int out_size, void* d_ws, size_t ws_size,
                              hipStream_t stream) {
    const float* x = (const float*)d_in[0];      // [B,4] f32
    const float* theta = (const float*)d_in[1];  // [8]   f32
    float* out = (float*)d_out;                  // [B,10] f32
    float* T = (float*)d_ws;                     // 160 floats scratch

    int nsamp = in_sizes[0] / 4;

    build_T<<<1, 192, 0, stream>>>(theta, T);

    int spb = TILES * 256;
    int blocks = (nsamp + spb - 1) / spb;
    vqc_main<<<blocks, 256, 0, stream>>>((const float4*)x, T, out, nsamp);
}